// Round 9
// baseline (1064.785 us; speedup 1.0000x reference)
//
#include <hip/hip_runtime.h>
#include <hip/hip_bf16.h>

#define NLAYER 4
#define NHEAD 8
#define CEMB 512
#define HS 64
#define VOCAB_N 32000
#define SEQT 2048
#define BATCH_N 2
#define MROWS (BATCH_N * SEQT)   /* 4096 */
#define WIN 64
#define NGLOB 16
#define NRAND 16

typedef __attribute__((ext_vector_type(8))) __bf16 bf16x8;
typedef __attribute__((ext_vector_type(4))) float f32x4;
typedef __attribute__((ext_vector_type(8))) unsigned short u16x8;

__device__ __forceinline__ unsigned short f2bf(float f) {
    unsigned u = __float_as_uint(f);
    u += 0x7fffu + ((u >> 16) & 1u);      // RNE
    return (unsigned short)(u >> 16);
}
__device__ __forceinline__ float bf2f(unsigned short v) {
    return __uint_as_float((unsigned)v << 16);
}
__device__ __forceinline__ bf16x8 asbf(u16x8 v) {
    return __builtin_bit_cast(bf16x8, v);
}

// async global->LDS, 16B per lane, dest = wave-uniform base + lane*16
__device__ __forceinline__ void stage16(const unsigned short* g, unsigned short* l) {
    __builtin_amdgcn_global_load_lds(
        (const __attribute__((address_space(1))) void*)g,
        (__attribute__((address_space(3))) void*)l, 16, 0, 0);
}

// ---------------------------------------------------------------- unified weight transpose
__global__ __launch_bounds__(256) void transpose_all_kernel(
    const float* __restrict__ Wq, const float* __restrict__ Wk,
    const float* __restrict__ Wv, const float* __restrict__ Wproj,
    const float* __restrict__ W1, const float* __restrict__ W2,
    const float* __restrict__ Wout,
    unsigned short* __restrict__ wqkvT, unsigned short* __restrict__ wprojT,
    unsigned short* __restrict__ w1T, unsigned short* __restrict__ w2T,
    unsigned short* __restrict__ woutT)
{
    __shared__ float tle[64][65];
    const int bid = blockIdx.x;
    const float* src; unsigned short* dst; int Ks, Ns, k0, n0;
    if (bid < 768) {
        const int tile = bid & 7, rest = bid >> 3;
        const int l = rest / 24, r2 = rest % 24;
        const int sel = r2 >> 3, h = r2 & 7;
        const float* W = (sel == 0) ? Wq : (sel == 1) ? Wk : Wv;
        src = W + (size_t)(l * 8 + h) * 512 * 64;
        dst = wqkvT + ((size_t)l * 1536 + sel * 512 + h * 64) * 512;
        Ks = 512; Ns = 64; k0 = tile * 64; n0 = 0;
    } else if (bid < 1024) {
        const int idx = bid - 768, l = idx >> 6, t6 = idx & 63;
        src = Wproj + (size_t)l * 512 * 512;
        dst = wprojT + (size_t)l * 512 * 512;
        Ks = 512; Ns = 512; k0 = (t6 >> 3) * 64; n0 = (t6 & 7) * 64;
    } else if (bid < 2048) {
        const int idx = bid - 1024, l = idx >> 8, t8 = idx & 255;
        src = W1 + (size_t)l * 512 * 2048;
        dst = w1T + (size_t)l * 2048 * 512;
        Ks = 512; Ns = 2048; k0 = (t8 >> 5) * 64; n0 = (t8 & 31) * 64;
    } else if (bid < 3072) {
        const int idx = bid - 2048, l = idx >> 8, t8 = idx & 255;
        src = W2 + (size_t)l * 2048 * 512;
        dst = w2T + (size_t)l * 512 * 2048;
        Ks = 2048; Ns = 512; k0 = (t8 >> 3) * 64; n0 = (t8 & 7) * 64;
    } else {
        const int idx = bid - 3072;
        src = Wout; dst = woutT;
        Ks = 512; Ns = 32000; k0 = (idx / 500) * 64; n0 = (idx % 500) * 64;
    }
    const int tid = threadIdx.x;
    #pragma unroll
    for (int i = 0; i < 16; ++i) {
        const int idx = tid + i * 256;
        const int r = idx >> 6, c = idx & 63;
        tle[r][c] = src[(size_t)(k0 + r) * Ns + n0 + c];
    }
    __syncthreads();
    #pragma unroll
    for (int i = 0; i < 16; ++i) {
        const int idx = tid + i * 256;
        const int c = idx >> 6, r = idx & 63;
        dst[(size_t)(n0 + c) * Ks + k0 + r] = f2bf(tle[r][c]);
    }
}

// ---------------------------------------------------------------- embedding
__global__ __launch_bounds__(256) void embed_kernel(
    const float* __restrict__ tok_emb, const float* __restrict__ pos_emb,
    const int* __restrict__ toks, float* __restrict__ x)
{
    int i = blockIdx.x * 256 + threadIdx.x;
    int m = i >> 7;
    int c = (i & 127) << 2;
    int tok = toks[m];
    const float4 a = *(const float4*)&tok_emb[(size_t)tok * CEMB + c];
    const float4 p = *(const float4*)&pos_emb[(size_t)(m & (SEQT - 1)) * CEMB + c];
    float4 o;
    o.x = a.x + p.x; o.y = a.y + p.y; o.z = a.z + p.z; o.w = a.w + p.w;
    *(float4*)&x[(size_t)m * CEMB + c] = o;
}

// ---------------------------------------------------------------- layernorm
__global__ __launch_bounds__(256) void ln_kernel(
    const float* __restrict__ x, const float* __restrict__ g,
    const float* __restrict__ b, unsigned short* __restrict__ out)
{
    const int wave = threadIdx.x >> 6, lane = threadIdx.x & 63;
    const int m = blockIdx.x * 4 + wave;
    const float* row = x + (size_t)m * CEMB;
    const float4 v0 = *(const float4*)&row[lane * 8];
    const float4 v1 = *(const float4*)&row[lane * 8 + 4];
    float s  = v0.x + v0.y + v0.z + v0.w + v1.x + v1.y + v1.z + v1.w;
    float s2 = v0.x*v0.x + v0.y*v0.y + v0.z*v0.z + v0.w*v0.w
             + v1.x*v1.x + v1.y*v1.y + v1.z*v1.z + v1.w*v1.w;
    #pragma unroll
    for (int off = 32; off > 0; off >>= 1) {
        s  += __shfl_xor(s, off);
        s2 += __shfl_xor(s2, off);
    }
    const float mu  = s * (1.f / CEMB);
    const float var = s2 * (1.f / CEMB) - mu * mu;
    const float rs  = rsqrtf(var + 1e-5f);
    const float vals[8] = {v0.x, v0.y, v0.z, v0.w, v1.x, v1.y, v1.z, v1.w};
    u16x8 o;
    #pragma unroll
    for (int j = 0; j < 8; ++j)
        o[j] = f2bf((vals[j] - mu) * rs * g[lane * 8 + j] + b[lane * 8 + j]);
    *(u16x8*)&out[(size_t)m * CEMB + lane * 8] = o;
}

// ---------------------------------------------------------------- MFMA GEMM (round-8, triple-buffer counted vmcnt)
template<int MODE, int NF, int SWZ>
__global__ __launch_bounds__(256) void gemm_kernel(
    const unsigned short* __restrict__ A, const unsigned short* __restrict__ Bt,
    const float* __restrict__ bias, const float* resid, void* outp,
    int M, int N, int K)
{
    __shared__ unsigned short sa[3][128 * 32];
    __shared__ unsigned short sb[3][NF * 32 * 32];
    const int tid = threadIdx.x;
    const int lane = tid & 63;
    const int wave = tid >> 6;
    const int wr = wave >> 1, wc = wave & 1;

    int bx = blockIdx.x, by = blockIdx.y;
    if (SWZ == 2) {
        const int flat = by * gridDim.x + bx;
        const int q = (gridDim.x * gridDim.y) >> 3;
        const int nl = (flat & 7) * q + (flat >> 3);
        by = nl & 31;
        bx = nl >> 5;
    }
    const int m0 = by * 128;
    const int n0 = bx * (NF * 32);

    const int c0a = (wave * 2) * 64 + lane;
    const int c1a = (wave * 2 + 1) * 64 + lane;
    const int r0 = c0a >> 2, kk0 = (c0a & 3) * 8;
    const int r1 = c1a >> 2, kk1 = (c1a & 3) * 8;
    const unsigned short* ga0 = A + (size_t)(m0 + r0) * K + kk0;
    const unsigned short* ga1 = A + (size_t)(m0 + r1) * K + kk1;
    const int o0 = (wave * 2) * 512;
    const int o1 = (wave * 2 + 1) * 512;
    const int cb0 = (NF == 4) ? c0a : wave * 64 + lane;
    const int cb1 = c1a;
    const int rb0 = cb0 >> 2, kb0 = (cb0 & 3) * 8;
    const int rb1 = cb1 >> 2, kb1 = (cb1 & 3) * 8;
    const unsigned short* gb0 = Bt + (size_t)(n0 + rb0) * K + kb0;
    const unsigned short* gb1 = Bt + (size_t)(n0 + rb1) * K + kb1;
    const int ob0 = (NF == 4) ? o0 : wave * 512;
    const int ob1 = o1;

    f32x4 acc[4][NF] = {};
    const int kro = (lane >> 4) * 8;
    const int fr = lane & 15;

    auto STAGE = [&](int tile, int buf) {
        const int kk = tile << 5;
        stage16(ga0 + kk, &sa[buf][o0]);
        stage16(ga1 + kk, &sa[buf][o1]);
        stage16(gb0 + kk, &sb[buf][ob0]);
        if constexpr (NF == 4) stage16(gb1 + kk, &sb[buf][ob1]);
    };

    const int nt = K >> 5;
    STAGE(0, 0);
    STAGE(1, 1);

    int cur = 0;
    for (int t = 0; t < nt; ++t) {
        if (t + 1 < nt) {
            if constexpr (NF == 2) asm volatile("s_waitcnt vmcnt(3)" ::: "memory");
            else                   asm volatile("s_waitcnt vmcnt(4)" ::: "memory");
        } else {
            asm volatile("s_waitcnt vmcnt(0)" ::: "memory");
        }
        __builtin_amdgcn_s_barrier();
        __builtin_amdgcn_sched_barrier(0);

        if (t + 2 < nt) {
            int b2 = cur + 2; if (b2 >= 3) b2 -= 3;
            STAGE(t + 2, b2);
        }

        bf16x8 af[4], bfr[NF];
        #pragma unroll
        for (int i = 0; i < 4; ++i)
            af[i] = *reinterpret_cast<const bf16x8*>(&sa[cur][(wr * 64 + i * 16 + fr) * 32 + kro]);
        #pragma unroll
        for (int i = 0; i < NF; ++i)
            bfr[i] = *reinterpret_cast<const bf16x8*>(&sb[cur][(wc * (NF * 16) + i * 16 + fr) * 32 + kro]);
        #pragma unroll
        for (int mi = 0; mi < 4; ++mi)
            #pragma unroll
            for (int ni = 0; ni < NF; ++ni)
                acc[mi][ni] = __builtin_amdgcn_mfma_f32_16x16x32_bf16(af[mi], bfr[ni], acc[mi][ni], 0, 0, 0);

        cur = (cur == 2) ? 0 : cur + 1;
    }

    #pragma unroll
    for (int mi = 0; mi < 4; ++mi) {
        #pragma unroll
        for (int ni = 0; ni < NF; ++ni) {
            const int gc = n0 + wc * (NF * 16) + ni * 16 + fr;
            const float bv = (MODE != 0) ? bias[gc] : 0.f;
            #pragma unroll
            for (int r = 0; r < 4; ++r) {
                const int gr = m0 + wr * 64 + mi * 16 + (lane >> 4) * 4 + r;
                float v = acc[mi][ni][r] + bv;
                if (MODE == 1) v += resid[(size_t)gr * N + gc];
                if (MODE == 2) v = fmaxf(v, 0.f);
                if (MODE == 0 || MODE == 2) {
                    ((unsigned short*)outp)[(size_t)gr * N + gc] = f2bf(v);
                } else {
                    ((float*)outp)[(size_t)gr * N + gc] = v;
                }
            }
        }
    }
}

// ---------------------------------------------------------------- sparse attention v5 (MFMA)
// Block = (b, h, 64 queries) = 4 waves x 16 queries. Per wave:
//   scores S[16 q][96 slots]: slots 0..79 = window cols tq0-64+j, slots 80..95 = global cols.
//   QK: 12 MFMA, B-frags direct from global K (contiguous in d). PV: 12 MFMA from LDS Vt.
//   Random cols: scalar, 4 lanes/query, shfl dedup, merged via per-wave LDS scalars.
#define VTS 168
#define PSS 104
#define OSS 68
__global__ __launch_bounds__(256) void attn_kernel(
    const unsigned short* __restrict__ qkv, const int* __restrict__ rc,
    unsigned short* __restrict__ attnout)
{
    __shared__ unsigned short Vt[64 * VTS];     // Vt[d][s]: s<128 col=t0-64+s, s>=128 global s-128
    __shared__ unsigned short Ps[4][16 * PSS];  // P bf16 per wave [q][96]
    __shared__ float Osh[4][16 * OSS];          // O f32 per wave [q][64]
    __shared__ unsigned short rWs[4][16][16];   // random weights bf16
    __shared__ short rCs[4][16][16];            // random cols
    __shared__ float qmaxr[4][16];
    __shared__ float qsumr[4][16];
    __shared__ float qinvA[4][16];

    const int tid = threadIdx.x;
    const int wv = tid >> 6, lane = tid & 63;
    const int l15 = lane & 15, lq = lane >> 4;
    const int bid = blockIdx.x;
    const int tg = bid & 31;
    const int h = (bid >> 5) & 7;
    const int b = bid >> 8;
    const int t0 = tg * 64;
    const int tq0 = t0 + wv * 16;

    const unsigned short* qb = qkv + (size_t)b * SEQT * 1536 + h * 64;
    const unsigned short* kb = qb + 512;
    const unsigned short* vb = qb + 1024;

    // ---- stage Vt (block-cooperative transpose): 8 d-chunks x 144 s
    for (int idx = tid; idx < 1152; idx += 256) {
        const int j = idx / 144;          // d-chunk 0..7
        const int s = idx - j * 144;      // 0..143
        int col = (s < 128) ? (t0 - 64 + s) : (s - 128);
        if (col < 0) col = 0;
        const u16x8 v = *(const u16x8*)&vb[(size_t)col * 1536 + j * 8];
        #pragma unroll
        for (int e = 0; e < 8; ++e)
            Vt[(j * 8 + e) * VTS + s] = v[e];
    }

    // ---- QK MFMA: A = Q frags (global), B = K col-frags (global)
    const int qrow = tq0 + l15;
    const u16x8 a0 = *(const u16x8*)&qb[(size_t)qrow * 1536 + lq * 8];
    const u16x8 a1 = *(const u16x8*)&qb[(size_t)qrow * 1536 + 32 + lq * 8];

    f32x4 sfr[6] = {};
    #pragma unroll
    for (int tile = 0; tile < 6; ++tile) {
        int c = (tile < 5) ? (tq0 - 64 + tile * 16 + l15) : l15;
        if (c < 0) c = 0;
        const unsigned short* kr = &kb[(size_t)c * 1536 + lq * 8];
        const u16x8 b0 = *(const u16x8*)&kr[0];
        const u16x8 b1 = *(const u16x8*)&kr[32];
        sfr[tile] = __builtin_amdgcn_mfma_f32_16x16x32_bf16(asbf(a0), asbf(b0), sfr[tile], 0, 0, 0);
        sfr[tile] = __builtin_amdgcn_mfma_f32_16x16x32_bf16(asbf(a1), asbf(b1), sfr[tile], 0, 0, 0);
    }

    // ---- mask + per-q window max (lane holds q=lq*4+r, slot j=tile*16+l15)
    float sw[24];
    float mxw[4] = {-1e30f, -1e30f, -1e30f, -1e30f};
    #pragma unroll
    for (int tile = 0; tile < 6; ++tile) {
        #pragma unroll
        for (int r = 0; r < 4; ++r) {
            const int dq = lq * 4 + r;
            float v = sfr[tile][r] * 0.125f;
            bool ok;
            if (tile < 5) {
                const int j = tile * 16 + l15;
                const int c = tq0 - 64 + j;
                ok = (j >= dq + 1) && (j <= dq + 64) && (c >= NGLOB);
            } else {
                ok = (l15 <= tq0 + dq);
            }
            v = ok ? v : -1e30f;
            sw[tile * 4 + r] = v;
            mxw[r] = fmaxf(mxw[r], v);
        }
    }
    #pragma unroll
    for (int r = 0; r < 4; ++r)
        #pragma unroll
        for (int off = 1; off < 16; off <<= 1)
            mxw[r] = fmaxf(mxw[r], __shfl_xor(mxw[r], off));

    // ---- random raw scores (4 lanes/query, slots (lane&3)+4i)
    const int myq = lane >> 2;
    const int tq = tq0 + myq;
    u16x8 qr[8];
    #pragma unroll
    for (int j = 0; j < 8; ++j)
        qr[j] = *(const u16x8*)&qb[(size_t)tq * 1536 + j * 8];

    int mycol[4]; bool mval[4];
    #pragma unroll
    for (int i = 0; i < 4; ++i) {
        const int slot = (lane & 3) + 4 * i;
        const int c = rc[((size_t)h * SEQT + tq) * NRAND + slot];
        mycol[i] = c;
        mval[i] = (c >= NGLOB) && (c <= tq - WIN);
    }
    #pragma unroll
    for (int k = 0; k < 4; ++k) {
        #pragma unroll
        for (int i2 = 0; i2 < 4; ++i2) {
            const int oc = __shfl(mycol[i2], (lane & ~3) + k);
            const int os = k + 4 * i2;
            #pragma unroll
            for (int i = 0; i < 4; ++i)
                if (oc == mycol[i] && os < (lane & 3) + 4 * i) mval[i] = false;
        }
    }
    float sraw[4];
    #pragma unroll
    for (int i = 0; i < 4; ++i) {
        float s = -1e30f;
        if (mval[i]) {
            float d = 0.f;
            const unsigned short* kr = &kb[(size_t)mycol[i] * 1536];
            #pragma unroll
            for (int j = 0; j < 8; ++j) {
                const u16x8 kc = *(const u16x8*)&kr[j * 8];
                #pragma unroll
                for (int e = 0; e < 8; ++e)
                    d += bf2f(kc[e]) * bf2f(qr[j][e]);
            }
            s = d * 0.125f;
        }
        sraw[i] = s;
    }
    float m4 = fmaxf(fmaxf(sraw[0], sraw[1]), fmaxf(sraw[2], sraw[3]));
    m4 = fmaxf(m4, __shfl_xor(m4, 1));
    m4 = fmaxf(m4, __shfl_xor(m4, 2));
    if ((lane & 3) == 0) qmaxr[wv][myq] = m4;

    // ---- combine maxes (window layout), publish
    float mx[4];
    #pragma unroll
    for (int r = 0; r < 4; ++r) {
        const float rm = qmaxr[wv][lq * 4 + r];
        mx[r] = fmaxf(mxw[r], rm);
        if (l15 == 0) qmaxr[wv][lq * 4 + r] = mx[r];
    }

    // ---- random exp/sum/store (random layout)
    const float qm = qmaxr[wv][myq];
    float s4 = 0.f;
    float er[4];
    #pragma unroll
    for (int i = 0; i < 4; ++i) {
        er[i] = mval[i] ? __expf(sraw[i] - qm) : 0.f;
        s4 += er[i];
    }
    s4 += __shfl_xor(s4, 1);
    s4 += __shfl_xor(s4, 2);
    if ((lane & 3) == 0) qsumr[wv][myq] = s4;
    #pragma unroll
    for (int i = 0; i < 4; ++i) {
        rWs[wv][myq][(lane & 3) + 4 * i] = f2bf(er[i]);
        rCs[wv][myq][(lane & 3) + 4 * i] = (short)mycol[i];
    }

    // ---- window exp/sum + inv + P write (window layout)
    #pragma unroll
    for (int r = 0; r < 4; ++r) {
        float sm = 0.f;
        #pragma unroll
        for (int tile = 0; tile < 6; ++tile) {
            const float e = __expf(sw[tile * 4 + r] - mx[r]);
            sw[tile * 4 + r] = e;
            sm += e;
        }
        #pragma unroll
        for (int off = 1; off < 16; off <<= 1) sm += __shfl_xor(sm, off);
        const float tot = sm + qsumr[wv][lq * 4 + r];
        const float iv = 1.f / tot;
        if (l15 == 0) qinvA[wv][lq * 4 + r] = iv;
    }
    #pragma unroll
    for (int tile = 0; tile < 6; ++tile)
        #pragma unroll
        for (int r = 0; r < 4; ++r)
            Ps[wv][(lq * 4 + r) * PSS + tile * 16 + l15] = f2bf(sw[tile * 4 + r]);

    __syncthreads();   // Vt staged by whole block; P/O etc are per-wave

    // ---- PV MFMA: A = P frags (LDS), B = Vt frags (LDS)
    f32x4 of[4] = {};
    #pragma unroll
    for (int kf = 0; kf < 3; ++kf) {
        const bf16x8 af = *reinterpret_cast<const bf16x8*>(&Ps[wv][l15 * PSS + kf * 32 + lq * 8]);
        const int ks0 = kf * 32 + lq * 8;
        const int s0 = (ks0 < 80) ? (wv * 16 + ks0) : (ks0 + 48);
        #pragma unroll
        for (int nt = 0; nt < 4; ++nt) {
            const bf16x8 bv = *reinterpret_cast<const bf16x8*>(&Vt[(nt * 16 + l15) * VTS + s0]);
            of[nt] = __builtin_amdgcn_mfma_f32_16x16x32_bf16(af, bv, of[nt], 0, 0, 0);
        }
    }
    #pragma unroll
    for (int nt = 0; nt < 4; ++nt)
        #pragma unroll
        for (int r = 0; r < 4; ++r)
            Osh[wv][(lq * 4 + r) * OSS + nt * 16 + l15] = of[nt][r];

    // ---- output: O + random PV (old layout, lane = d), normalize
    for (int q = 0; q < 16; ++q) {
        const int m = b * SEQT + tq0 + q;
        float acc = Osh[wv][q * OSS + lane];
        #pragma unroll 4
        for (int s2 = 0; s2 < 16; ++s2) {
            const float w = bf2f(rWs[wv][q][s2]);
            if (w != 0.f) {
                const int c = rCs[wv][q][s2];
                acc += w * bf2f(vb[(size_t)c * 1536 + lane]);
            }
        }
        attnout[(size_t)m * CEMB + h * 64 + lane] = f2bf(acc * qinvA[wv][q]);
    }
}

// ---------------------------------------------------------------- host
extern "C" void kernel_launch(void* const* d_in, const int* in_sizes, int n_in,
                              void* d_out, int out_size, void* d_ws, size_t ws_size,
                              hipStream_t stream)
{
    const float* tok_emb = (const float*)d_in[0];
    const float* pos_emb = (const float*)d_in[1];
    const float* Wq    = (const float*)d_in[2];
    const float* Wk    = (const float*)d_in[3];
    const float* Wv    = (const float*)d_in[4];
    const float* Wproj = (const float*)d_in[5];
    const float* bproj = (const float*)d_in[6];
    const float* ln1g  = (const float*)d_in[7];
    const float* ln1b  = (const float*)d_in[8];
    const float* ln2g  = (const float*)d_in[9];
    const float* ln2b  = (const float*)d_in[10];
    const float* W1    = (const float*)d_in[11];
    const float* b1    = (const float*)d_in[12];
    const float* W2    = (const float*)d_in[13];
    const float* b2    = (const float*)d_in[14];
    const float* lnfg  = (const float*)d_in[15];
    const float* lnfb  = (const float*)d_in[16];
    const float* Wout  = (const float*)d_in[17];
    const float* bout  = (const float*)d_in[18];
    const int*   toks  = (const int*)d_in[19];
    const int*   rcols = (const int*)d_in[20];
    (void)in_sizes; (void)n_in; (void)out_size; (void)ws_size;

    char* ws = (char*)d_ws;
    size_t off = 0;
    auto ALLOC = [&](size_t bytes) -> void* {
        void* p = ws + off;
        off += (bytes + 255) & ~(size_t)255;
        return p;
    };
    float*          x      = (float*)ALLOC((size_t)MROWS * CEMB * 4);
    unsigned short* xnbf   = (unsigned short*)ALLOC((size_t)MROWS * CEMB * 2);
    unsigned short* qkv    = (unsigned short*)ALLOC((size_t)MROWS * 1536 * 2);
    unsigned short* attnbf = (unsigned short*)ALLOC((size_t)MROWS * CEMB * 2);
    unsigned short* hbf    = (unsigned short*)ALLOC((size_t)MROWS * 2048 * 2);
    unsigned short* wqkvT  = (unsigned short*)ALLOC((size_t)NLAYER * 1536 * 512 * 2);
    unsigned short* wprojT = (unsigned short*)ALLOC((size_t)NLAYER * 512 * 512 * 2);
    unsigned short* w1T    = (unsigned short*)ALLOC((size_t)NLAYER * 2048 * 512 * 2);
    unsigned short* w2T    = (unsigned short*)ALLOC((size_t)NLAYER * 512 * 2048 * 2);
    unsigned short* woutT  = (unsigned short*)ALLOC((size_t)VOCAB_N * 512 * 2);

    transpose_all_kernel<<<7072, 256, 0, stream>>>(
        Wq, Wk, Wv, Wproj, W1, W2, Wout, wqkvT, wprojT, w1T, w2T, woutT);

    embed_kernel<<<2048, 256, 0, stream>>>(tok_emb, pos_emb, toks, x);

    for (int l = 0; l < NLAYER; ++l) {
        ln_kernel<<<1024, 256, 0, stream>>>(x, ln1g + l * CEMB, ln1b + l * CEMB, xnbf);
        gemm_kernel<0, 2, 0><<<dim3(24, 32), 256, 0, stream>>>(
            xnbf, wqkvT + (size_t)l * 1536 * 512, nullptr, nullptr, qkv, MROWS, 1536, 512);
        attn_kernel<<<512, 256, 0, stream>>>(qkv, rcols + (size_t)l * NHEAD * SEQT * NRAND, attnbf);
        gemm_kernel<1, 2, 0><<<dim3(8, 32), 256, 0, stream>>>(
            attnbf, wprojT + (size_t)l * 512 * 512, bproj + l * CEMB, x, x, MROWS, 512, 512);
        ln_kernel<<<1024, 256, 0, stream>>>(x, ln2g + l * CEMB, ln2b + l * CEMB, xnbf);
        gemm_kernel<2, 4, 0><<<dim3(16, 32), 256, 0, stream>>>(
            xnbf, w1T + (size_t)l * 2048 * 512, b1 + l * 2048, nullptr, hbf, MROWS, 2048, 512);
        gemm_kernel<1, 2, 0><<<dim3(8, 32), 256, 0, stream>>>(
            hbf, w2T + (size_t)l * 512 * 2048, b2 + l * CEMB, x, x, MROWS, 512, 2048);
    }
    ln_kernel<<<1024, 256, 0, stream>>>(x, lnfg, lnfb, xnbf);
    gemm_kernel<3, 4, 2><<<dim3(250, 32), 256, 0, stream>>>(
        xnbf, woutT, bout, nullptr, d_out, MROWS, VOCAB_N, 512);
}